// Round 16
// baseline (70.614 us; speedup 1.0000x reference)
//
#include <hip/hip_runtime.h>

// upfirdn2d: UP=1, DOWN=2, PAD=5, 12x12 separable sym6 kernel.
// v14: r15's 2.31x read redundancy (74 rows / 32 out-rows via sv[10] carry)
//      + 4 blocks/CU restored. LDS halved to a 32-row double-use buffer
//      (34.5 KB): phase A fills rows {0-15,32-47} -> H0; phase B fills
//      {16-31,48-63} -> H1. Streaming retirement (store acc[ri] at its
//      last tap, static indices) keeps ~6 accs live -> VGPR <= ~128 for
//      16 waves/CU. XCD-chunked swizzle, nt f32x4 stores.

#define H_IN  256
#define W_IN  256
#define H_OUT 128
#define W_OUT 128
#define KTAP  12
#define VSTR  276    // LDS row stride in words
#define FG    68     // frame float4-groups per row (words 0..271 <-> cols -8..263)
#define NTHR  256

typedef float f32x4 __attribute__((ext_vector_type(4)));

__global__ __launch_bounds__(NTHR)
void upfirdn2d_sym6(const float* __restrict__ x,
                    const float* __restrict__ k2d,
                    float* __restrict__ out) {
    __shared__ float vs[32 * VSTR];   // 34.5 KB double-use buffer
    __shared__ float rsum[KTAP];

    const int tid = threadIdx.x;

    // --- cheap tap derivation: k2d[p][q]=h[p]h[q]; w[p]=h[11-p]=rowsum[11-p]/sqrt(tot)
    if (tid < KTAP) {
        const float4* kp = reinterpret_cast<const float4*>(k2d + 12 * tid);
        float4 a = kp[0], b = kp[1], c = kp[2];
        rsum[tid] = ((a.x + a.y) + (a.z + a.w))
                  + ((b.x + b.y) + (b.z + b.w))
                  + ((c.x + c.y) + (c.z + c.w));
    }
    __syncthreads();
    float w[KTAP];
    {
        float tot = 0.f;
        #pragma unroll
        for (int q = 0; q < KTAP; ++q) tot += rsum[q];
        const float r = rsqrtf(tot);
        #pragma unroll
        for (int p = 0; p < KTAP; ++p) w[p] = rsum[KTAP - 1 - p] * r;
    }

    // --- XCD-chunked bijective swizzle (2048 blocks = 8 XCDs x 256)
    const int bid = blockIdx.x;            // 0..2047
    const int nb  = (bid & 7) * 256 + (bid >> 3);
    const int img = nb >> 1;               // 0..1023
    const int ti  = nb & 1;                // 0..1 (64 out-rows each)

    const float* xim = x + (size_t)img * (H_IN * W_IN);
    float* oim = out + (size_t)img * (H_OUT * W_OUT);

    // --- V-task decode (136 tasks: sg 0..1 x cg 0..67)
    const int sg  = (tid < FG) ? 0 : 1;              // tid/68 for tid<136
    const int cg  = tid - sg * FG;
    const int col = -8 + 4 * cg;
    const bool colok = (unsigned)col < (unsigned)W_IN;
    const int gr0 = 128 * ti + 64 * sg - 5;          // first input row of task
    const bool vactive = (tid < 136);

    const float* rp = xim + (size_t)gr0 * W_IN + col;
    float* vrow = &vs[(size_t)(16 * sg) * VSTR + 4 * cg];  // buf rows sg*16..+15
    float4 sv[10];                                   // carry rows 32..41

    // ================= phase A: rows gr0..gr0+41 -> buf rows sg*16+0..15
    if (vactive) {
        float4 acc[16];
        #pragma unroll
        for (int k = 0; k < 16; ++k) acc[k] = make_float4(0.f, 0.f, 0.f, 0.f);

        #pragma unroll
        for (int rr = 0; rr < 42; ++rr) {
            const int gr = gr0 + rr;
            float4 v = make_float4(0.f, 0.f, 0.f, 0.f);
            if (colok && (unsigned)gr < (unsigned)H_IN)
                v = *reinterpret_cast<const float4*>(rp);
            rp += W_IN;
            if (rr >= 32) sv[rr - 32] = v;           // compile-time index
            #pragma unroll
            for (int ri = 0; ri < 16; ++ri) {
                const int p = rr - 2 * ri;           // compile-time tap
                if (p >= 0 && p < KTAP) {
                    acc[ri].x = fmaf(w[p], v.x, acc[ri].x);
                    acc[ri].y = fmaf(w[p], v.y, acc[ri].y);
                    acc[ri].z = fmaf(w[p], v.z, acc[ri].z);
                    acc[ri].w = fmaf(w[p], v.w, acc[ri].w);
                    if (p == KTAP - 1)               // retire: acc[ri] dead after
                        *reinterpret_cast<float4*>(vrow + (size_t)ri * VSTR) = acc[ri];
                }
            }
        }
    }
    __syncthreads();

    // ================= H phase 0: buf rows 0..31 -> out-rows {0..15, 32..47}
    for (int t = tid; t < 512; t += NTHR) {
        const int i = t >> 4;                        // buf row 0..31
        const int g = t & 15;
        float f[32];
        #pragma unroll
        for (int m = 0; m < 8; ++m) {
            float4 v4 = *reinterpret_cast<const float4*>(&vs[i * VSTR + 16 * g + 4 * m]);
            f[4*m+0] = v4.x; f[4*m+1] = v4.y; f[4*m+2] = v4.z; f[4*m+3] = v4.w;
        }
        float o[8];
        #pragma unroll
        for (int jj = 0; jj < 8; ++jj) {
            float a = 0.f;
            #pragma unroll
            for (int q = 0; q < KTAP; ++q)
                a = fmaf(w[q], f[2*jj + 3 + q], a);
            o[jj] = a;
        }
        const int orow = 64 * ti + i + (i & 16);     // i<16: i ; i>=16: i+16
        const int ocol = 8 * g;
        f32x4 o0 = { o[0], o[1], o[2], o[3] };
        f32x4 o1 = { o[4], o[5], o[6], o[7] };
        float* dst = oim + (size_t)orow * W_OUT + ocol;
        __builtin_nontemporal_store(o0, reinterpret_cast<f32x4*>(dst));
        __builtin_nontemporal_store(o1, reinterpret_cast<f32x4*>(dst + 4));
    }
    __syncthreads();   // H0 reads done before phase B overwrites buf

    // ================= phase B: rows gr0+32..73 (first 10 from sv) -> buf
    if (vactive) {
        float4 acc[16];
        #pragma unroll
        for (int k = 0; k < 16; ++k) acc[k] = make_float4(0.f, 0.f, 0.f, 0.f);

        #pragma unroll
        for (int rr2 = 0; rr2 < 42; ++rr2) {
            const int gr = gr0 + 32 + rr2;
            float4 v;
            if (rr2 < 10) {
                v = sv[rr2];                         // compile-time index
            } else {
                v = make_float4(0.f, 0.f, 0.f, 0.f);
                if (colok && (unsigned)gr < (unsigned)H_IN)
                    v = *reinterpret_cast<const float4*>(rp);
                rp += W_IN;
            }
            #pragma unroll
            for (int ri = 0; ri < 16; ++ri) {
                const int p = rr2 - 2 * ri;          // compile-time tap
                if (p >= 0 && p < KTAP) {
                    acc[ri].x = fmaf(w[p], v.x, acc[ri].x);
                    acc[ri].y = fmaf(w[p], v.y, acc[ri].y);
                    acc[ri].z = fmaf(w[p], v.z, acc[ri].z);
                    acc[ri].w = fmaf(w[p], v.w, acc[ri].w);
                    if (p == KTAP - 1)
                        *reinterpret_cast<float4*>(vrow + (size_t)ri * VSTR) = acc[ri];
                }
            }
        }
    }
    __syncthreads();

    // ================= H phase 1: buf rows 0..31 -> out-rows {16..31, 48..63}
    for (int t = tid; t < 512; t += NTHR) {
        const int i = t >> 4;
        const int g = t & 15;
        float f[32];
        #pragma unroll
        for (int m = 0; m < 8; ++m) {
            float4 v4 = *reinterpret_cast<const float4*>(&vs[i * VSTR + 16 * g + 4 * m]);
            f[4*m+0] = v4.x; f[4*m+1] = v4.y; f[4*m+2] = v4.z; f[4*m+3] = v4.w;
        }
        float o[8];
        #pragma unroll
        for (int jj = 0; jj < 8; ++jj) {
            float a = 0.f;
            #pragma unroll
            for (int q = 0; q < KTAP; ++q)
                a = fmaf(w[q], f[2*jj + 3 + q], a);
            o[jj] = a;
        }
        const int orow = 64 * ti + i + (i & 16) + 16;
        const int ocol = 8 * g;
        f32x4 o0 = { o[0], o[1], o[2], o[3] };
        f32x4 o1 = { o[4], o[5], o[6], o[7] };
        float* dst = oim + (size_t)orow * W_OUT + ocol;
        __builtin_nontemporal_store(o0, reinterpret_cast<f32x4*>(dst));
        __builtin_nontemporal_store(o1, reinterpret_cast<f32x4*>(dst + 4));
    }
}

extern "C" void kernel_launch(void* const* d_in, const int* in_sizes, int n_in,
                              void* d_out, int out_size, void* d_ws, size_t ws_size,
                              hipStream_t stream) {
    const float* x   = (const float*)d_in[0];
    const float* k2d = (const float*)d_in[1];
    float* out       = (float*)d_out;

    // 2 full-width tiles (64x128) per image, 1024 images = 2048 blocks
    dim3 grid(2048);
    dim3 block(NTHR);
    upfirdn2d_sym6<<<grid, block, 0, stream>>>(x, k2d, out);
}

// Round 17
// 60.495 us; speedup vs baseline: 1.1673x; 1.1673x over previous
//
#include <hip/hip_runtime.h>

// upfirdn2d: UP=1, DOWN=2, PAD=5, 12x12 separable sym6 kernel.
// v13-restore (= r15, best @ 61.3us): 64x128 full-width tile, 2-phase V with
// sv[10] register carry (74 rows / 32 out-rows = 2.31x read redundancy),
// 42-iter/16-acc proven codegen shape (all indices compile-time), f32 LDS
// 64x276 (69 KB, 2 blocks/CU), XCD-chunked bijective swizzle, nt f32x4 stores.
// r16 (4-phase double-use buffer) regressed to 70.6us: barrier serialization
// outweighed the occupancy gain. Ledger: binder = issued vmem bytes @~6.5TB/s;
// occupancy/pipelining/prologue/decoupling all null.

#define H_IN  256
#define W_IN  256
#define H_OUT 128
#define W_OUT 128
#define KTAP  12
#define VSTR  276    // LDS row stride in words
#define FG    68     // frame float4-groups per row (words 0..271 <-> cols -8..263)
#define NTHR  256

typedef float f32x4 __attribute__((ext_vector_type(4)));

__global__ __launch_bounds__(NTHR)
void upfirdn2d_sym6(const float* __restrict__ x,
                    const float* __restrict__ k2d,
                    float* __restrict__ out) {
    __shared__ float vs[64 * VSTR];   // 69 KB
    __shared__ float rsum[KTAP];

    const int tid = threadIdx.x;

    // --- cheap tap derivation: k2d[p][q]=h[p]h[q]; w[p]=h[11-p]=rowsum[11-p]/sqrt(tot)
    if (tid < KTAP) {
        const float4* kp = reinterpret_cast<const float4*>(k2d + 12 * tid);
        float4 a = kp[0], b = kp[1], c = kp[2];
        rsum[tid] = ((a.x + a.y) + (a.z + a.w))
                  + ((b.x + b.y) + (b.z + b.w))
                  + ((c.x + c.y) + (c.z + c.w));
    }
    __syncthreads();
    float w[KTAP];
    {
        float tot = 0.f;
        #pragma unroll
        for (int q = 0; q < KTAP; ++q) tot += rsum[q];
        const float r = rsqrtf(tot);
        #pragma unroll
        for (int p = 0; p < KTAP; ++p) w[p] = rsum[KTAP - 1 - p] * r;
    }

    // --- XCD-chunked bijective swizzle (2048 blocks = 8 XCDs x 256):
    //     ti=0/1 of an image adjacent on the same XCD -> halo L2 reuse.
    const int bid = blockIdx.x;            // 0..2047
    const int nb  = (bid & 7) * 256 + (bid >> 3);
    const int img = nb >> 1;               // 0..1023
    const int ti  = nb & 1;                // 0..1 (64 out-rows each)

    const float* xim = x + (size_t)img * (H_IN * W_IN);
    float* oim = out + (size_t)img * (H_OUT * W_OUT);

    // ---- vertical pass: 136 tasks (sg 0..1 x cg 0..67); each task produces
    //      32 out-rows x 4 cols via two 16-row phases + 10-row register carry.
    if (tid < 136) {
        const int sg  = tid / FG;                        // 0..1
        const int cg  = tid - sg * FG;
        const int col = -8 + 4 * cg;                     // global col of float4
        const bool colok = (unsigned)col < (unsigned)W_IN;
        const int gr0 = 128 * ti + 64 * sg - 5;          // first input row
        const int lr0 = 32 * sg;                         // local out-row base

        const float* rp = xim + (size_t)gr0 * W_IN + col;
        float4 sv[10];                                   // carry rows 32..41

        // ---- phase A: input rows gr0+0..41 -> out-rows lr0+0..15
        {
            float4 acc[16];
            #pragma unroll
            for (int k = 0; k < 16; ++k) acc[k] = make_float4(0.f, 0.f, 0.f, 0.f);

            #pragma unroll
            for (int rr = 0; rr < 42; ++rr) {
                const int gr = gr0 + rr;
                float4 v = make_float4(0.f, 0.f, 0.f, 0.f);
                if (colok && (unsigned)gr < (unsigned)H_IN)
                    v = *reinterpret_cast<const float4*>(rp);
                rp += W_IN;
                if (rr >= 32) sv[rr - 32] = v;           // compile-time index
                #pragma unroll
                for (int ri = 0; ri < 16; ++ri) {
                    const int p = rr - 2 * ri;           // compile-time tap
                    if (p >= 0 && p < KTAP) {
                        acc[ri].x = fmaf(w[p], v.x, acc[ri].x);
                        acc[ri].y = fmaf(w[p], v.y, acc[ri].y);
                        acc[ri].z = fmaf(w[p], v.z, acc[ri].z);
                        acc[ri].w = fmaf(w[p], v.w, acc[ri].w);
                    }
                }
            }
            #pragma unroll
            for (int ri = 0; ri < 16; ++ri)
                *reinterpret_cast<float4*>(&vs[(lr0 + ri) * VSTR + 4 * cg]) = acc[ri];
        }

        // ---- phase B: input rows gr0+32..73 (first 10 from sv) -> out-rows lr0+16..31
        {
            float4 acc[16];
            #pragma unroll
            for (int k = 0; k < 16; ++k) acc[k] = make_float4(0.f, 0.f, 0.f, 0.f);

            #pragma unroll
            for (int rr2 = 0; rr2 < 42; ++rr2) {
                const int gr = gr0 + 32 + rr2;
                float4 v;
                if (rr2 < 10) {
                    v = sv[rr2];                         // compile-time index
                } else {
                    v = make_float4(0.f, 0.f, 0.f, 0.f);
                    if (colok && (unsigned)gr < (unsigned)H_IN)
                        v = *reinterpret_cast<const float4*>(rp);
                    rp += W_IN;
                }
                #pragma unroll
                for (int ri = 0; ri < 16; ++ri) {
                    const int p = rr2 - 2 * ri;          // compile-time tap
                    if (p >= 0 && p < KTAP) {
                        acc[ri].x = fmaf(w[p], v.x, acc[ri].x);
                        acc[ri].y = fmaf(w[p], v.y, acc[ri].y);
                        acc[ri].z = fmaf(w[p], v.z, acc[ri].z);
                        acc[ri].w = fmaf(w[p], v.w, acc[ri].w);
                    }
                }
            }
            #pragma unroll
            for (int ri = 0; ri < 16; ++ri)
                *reinterpret_cast<float4*>(&vs[(lr0 + 16 + ri) * VSTR + 4 * cg]) = acc[ri];
        }
    }
    __syncthreads();

    // ---- horizontal pass: 1024 tasks (i 0..63 x g 0..15), 8 outputs each
    for (int t = tid; t < 1024; t += NTHR) {
        const int i = t >> 4;
        const int g = t & 15;

        float f[32];
        #pragma unroll
        for (int m = 0; m < 8; ++m) {
            float4 v4 = *reinterpret_cast<const float4*>(&vs[i * VSTR + 16 * g + 4 * m]);
            f[4*m+0] = v4.x; f[4*m+1] = v4.y; f[4*m+2] = v4.z; f[4*m+3] = v4.w;
        }
        // output j = 8g+jj needs frame words 16g + 2jj+3 .. 16g + 2jj+14
        float o[8];
        #pragma unroll
        for (int jj = 0; jj < 8; ++jj) {
            float a = 0.f;
            #pragma unroll
            for (int q = 0; q < KTAP; ++q)
                a = fmaf(w[q], f[2*jj + 3 + q], a);
            o[jj] = a;
        }
        const int orow = 64 * ti + i;
        const int ocol = 8 * g;
        f32x4 o0 = { o[0], o[1], o[2], o[3] };
        f32x4 o1 = { o[4], o[5], o[6], o[7] };
        float* dst = oim + (size_t)orow * W_OUT + ocol;
        __builtin_nontemporal_store(o0, reinterpret_cast<f32x4*>(dst));
        __builtin_nontemporal_store(o1, reinterpret_cast<f32x4*>(dst + 4));
    }
}

extern "C" void kernel_launch(void* const* d_in, const int* in_sizes, int n_in,
                              void* d_out, int out_size, void* d_ws, size_t ws_size,
                              hipStream_t stream) {
    const float* x   = (const float*)d_in[0];
    const float* k2d = (const float*)d_in[1];
    float* out       = (float*)d_out;

    // 2 full-width tiles (64x128) per image, 1024 images = 2048 blocks
    dim3 grid(2048);
    dim3 block(NTHR);
    upfirdn2d_sym6<<<grid, block, 0, stream>>>(x, k2d, out);
}